// Round 13
// baseline (170.072 us; speedup 1.0000x reference)
//
#include <hip/hip_runtime.h>
#include <hip/hip_fp16.h>

#define CHUNK 2048        // edges per binA block (256 threads x 8)
#define NBUCK 391         // buckets of 128 nodes (dst>>7)
#define BCAP  8192        // per-bucket edge capacity (mean 4096, 64 sigma slack)
#define CCAP  (BCAP+2048) // csr region capacity (edges + self + per-row pad to x8)
#define NGEMM 784         // gemm tiles of 64 rows (covers N+1 = 50001)

using u32x4 = __attribute__((ext_vector_type(4))) unsigned int;

// L2-hygiene policy (r8/r10/r11 causal triple): nt ONLY on single-touch,
// full-line streams (csr reads in aggs: +30us win, r10). nt on reused data
// (r8: +16us) or on line-reused/partial-line accesses (r11: +27us) REGRESSES.

// Front: 256-thread blocks (r12->r13: was 512). gemm = 4 thr/row, 8 cols each
// (row's 4 lanes issue the SAME x address -> coalescer broadcast); binA =
// 8 edges/thread with paired 512-counter shfl-scan. Union LDS 16KB; grid 1568
// -> ~25 waves/CU (was 18.4): latency-bound front gets +33% TLP and 1/4 the
// per-thread serial chain in gemm.
union FrontSmem {
    struct { float Wsh[128 * 32]; } g;                       // 16 KB
    struct { int cnt[512]; int lbase[512]; int gbs[512]; int wsum[4];
             unsigned int stage[CHUNK]; } a;                 // 14 KB
};

__global__ __launch_bounds__(256)
void k_front(const float* __restrict__ x, const float* __restrict__ W,
             __half* __restrict__ h, int N,
             const int* __restrict__ src, const int* __restrict__ dst, int E,
             int* __restrict__ cursor, unsigned int* __restrict__ binned) {
    __shared__ FrontSmem sm;
    int bid = (int)blockIdx.x;
    int tid = threadIdx.x;
    bool isg = (bid & 1) == 0;        // even bids: 784 gemm blocks

    if (isg) {
        // ---- gemm path: 64 rows/block; thread = 1 row x 8 cols (4 thr/row)
        float* Wsh = sm.g.Wsh;
        for (int j = tid; j < 1024; j += 256)
            reinterpret_cast<float4*>(Wsh)[j] = reinterpret_cast<const float4*>(W)[j];
        __syncthreads();
        int r = tid >> 2;             // row in tile (0..63)
        int cg = tid & 3;             // col group: cols cg*8 .. cg*8+7
        int row = (bid >> 1) * 64 + r;
        const float4 z4 = make_float4(0.f, 0.f, 0.f, 0.f);
        float4 acc0 = z4, acc1 = z4;
        if (row < N) {
            const float4* xr = reinterpret_cast<const float4*>(x + (size_t)row * 128);
            float4 bufA[4], bufB[4];
            #pragma unroll
            for (int i = 0; i < 4; ++i) bufA[i] = xr[i];
            #pragma unroll
            for (int blk = 0; blk < 8; ++blk) {
                if (blk < 7) {
                    if ((blk & 1) == 0) {
                        #pragma unroll
                        for (int i = 0; i < 4; ++i) bufB[i] = xr[(blk + 1) * 4 + i];
                    } else {
                        #pragma unroll
                        for (int i = 0; i < 4; ++i) bufA[i] = xr[(blk + 1) * 4 + i];
                    }
                }
                #pragma unroll
                for (int i = 0; i < 4; ++i) {
                    float4 xv = ((blk & 1) == 0) ? bufA[i] : bufB[i];
                    const float* xp = reinterpret_cast<const float*>(&xv);
                    #pragma unroll
                    for (int j = 0; j < 4; ++j) {
                        float xj = xp[j];
                        const float4* wr = reinterpret_cast<const float4*>(
                            Wsh + ((blk * 4 + i) * 4 + j) * 32 + cg * 8);
                        float4 w0 = wr[0];
                        float4 w1 = wr[1];
                        acc0.x += xj * w0.x; acc0.y += xj * w0.y;
                        acc0.z += xj * w0.z; acc0.w += xj * w0.w;
                        acc1.x += xj * w1.x; acc1.y += xj * w1.y;
                        acc1.z += xj * w1.z; acc1.w += xj * w1.w;
                    }
                }
            }
        }
        if (row <= N) {   // row N (pad): acc stays zero -> zero row
            __half2 h0 = __floats2half2_rn(acc0.x, acc0.y);
            __half2 h1 = __floats2half2_rn(acc0.z, acc0.w);
            __half2 h2 = __floats2half2_rn(acc1.x, acc1.y);
            __half2 h3 = __floats2half2_rn(acc1.z, acc1.w);
            uint4 st;
            st.x = *reinterpret_cast<unsigned int*>(&h0);
            st.y = *reinterpret_cast<unsigned int*>(&h1);
            st.z = *reinterpret_cast<unsigned int*>(&h2);
            st.w = *reinterpret_cast<unsigned int*>(&h3);
            *reinterpret_cast<uint4*>(h + (size_t)row * 32 + cg * 8) = st;
        }
        return;
    }

    // ---- binA path: rank -> paired wave-shfl scan -> LDS stage -> run writes
    int abid = bid >> 1;              // odd bids: 784 slots, 782 used
    if (abid * CHUNK >= E) return;
    int* cnt = sm.a.cnt;
    int* lbase = sm.a.lbase;
    int* gbs = sm.a.gbs;
    unsigned int* stage = sm.a.stage;
    cnt[tid] = 0;
    cnt[tid + 256] = 0;
    __syncthreads();
    int base = abid * CHUNK;
    unsigned int pk[8];
    int rk[8];
    unsigned int mask = 0;
    #pragma unroll
    for (int i = 0; i < 2; ++i) {
        int e = base + i * 1024 + tid * 4;
        if (e + 3 < E) {
            int4 d4 = *reinterpret_cast<const int4*>(dst + e);
            int4 s4 = *reinterpret_cast<const int4*>(src + e);
            pk[i*4+0] = ((unsigned)d4.x << 16) | (unsigned)s4.x; rk[i*4+0] = atomicAdd(&cnt[d4.x >> 7], 1);
            pk[i*4+1] = ((unsigned)d4.y << 16) | (unsigned)s4.y; rk[i*4+1] = atomicAdd(&cnt[d4.y >> 7], 1);
            pk[i*4+2] = ((unsigned)d4.z << 16) | (unsigned)s4.z; rk[i*4+2] = atomicAdd(&cnt[d4.z >> 7], 1);
            pk[i*4+3] = ((unsigned)d4.w << 16) | (unsigned)s4.w; rk[i*4+3] = atomicAdd(&cnt[d4.w >> 7], 1);
            mask |= 0xFu << (i * 4);
        } else {
            for (int j = 0; j < 4; ++j) {
                int k = e + j;
                if (k < E) {
                    int d = dst[k], s = src[k];
                    pk[i*4+j] = ((unsigned)d << 16) | (unsigned)s;
                    rk[i*4+j] = atomicAdd(&cnt[d >> 7], 1);
                    mask |= 1u << (i * 4 + j);
                }
            }
        }
    }
    __syncthreads();
    // paired scan: thread handles counters 2tid, 2tid+1 (512 total, 4 waves)
    int c0 = cnt[2 * tid];
    int c1 = cnt[2 * tid + 1];
    int s = c0 + c1;
    int lid = tid & 63, wid = tid >> 6;
    int v = s;
    #pragma unroll
    for (int d = 1; d < 64; d <<= 1) {
        int u = __shfl_up(v, d, 64);
        if (lid >= d) v += u;
    }
    if (lid == 63) sm.a.wsum[wid] = v;
    __syncthreads();
    int pre = 0, tot = 0;
    #pragma unroll
    for (int w2 = 0; w2 < 4; ++w2) {
        int ws = sm.a.wsum[w2];
        tot += ws;
        if (w2 < wid) pre += ws;
    }
    int pairExcl = v + pre - s;        // exclusive start of pair 2tid
    lbase[2 * tid]     = pairExcl;
    lbase[2 * tid + 1] = pairExcl + c0;
    gbs[2 * tid]     = c0 ? atomicAdd(&cursor[2 * tid], c0) : 0;
    gbs[2 * tid + 1] = c1 ? atomicAdd(&cursor[2 * tid + 1], c1) : 0;
    int nvalid = tot;
    __syncthreads();
    #pragma unroll
    for (int i = 0; i < 8; ++i) {
        if (mask & (1u << i)) {
            int b = pk[i] >> 23;
            stage[lbase[b] + rk[i]] = pk[i];
        }
    }
    __syncthreads();
    for (int i = tid; i < nvalid; i += 256) {
        unsigned int v2 = stage[i];
        int b = v2 >> 23;
        binned[(size_t)b * BCAP + gbs[b] + (i - lbase[b])] = v2;   // regular: binB reuses
    }
}

// binB: one block per 128-node bucket. Single pass with rank recording.
__global__ __launch_bounds__(512)
void k_binB(const unsigned int* __restrict__ binned, const int* __restrict__ cursor,
            int* __restrict__ rowbeg, int* __restrict__ rowend, float* __restrict__ dinvg,
            unsigned short* __restrict__ csr, __half* __restrict__ hh, int N) {
    __shared__ int cnt[128];
    __shared__ int excls[128];
    __shared__ float dv[128];
    __shared__ int wsum2[2];
    int tid = threadIdx.x;
    int b = blockIdx.x;
    size_t ebase = (size_t)b * BCAP;
    int ne = cursor[b];
    if (tid < 128) cnt[tid] = 0;
    __syncthreads();
    unsigned int pk[16];
    int rk[16];
    #pragma unroll
    for (int ii = 0; ii < 16; ++ii) {
        int i = ii * 512 + tid;
        if (i < ne) {
            pk[ii] = binned[ebase + i];
            rk[ii] = atomicAdd(&cnt[(pk[ii] >> 16) & 127], 1);
        }
    }
    __syncthreads();
    int myc = 0, pcnt = 0;
    if (tid < 128) {
        myc = cnt[tid];
        pcnt = (myc + 1 + 7) & ~7;   // self + edges, padded to x8 (region layout)
    }
    int lid = tid & 63, wid2 = tid >> 6;
    int v = pcnt;
    if (tid < 128) {
        #pragma unroll
        for (int d = 1; d < 64; d <<= 1) {
            int u = __shfl_up(v, d, 64);
            if (lid >= d) v += u;
        }
        if (lid == 63) wsum2[wid2] = v;
    }
    __syncthreads();
    if (tid < 128 && wid2 == 1) v += wsum2[0];
    int cbase = b * CCAP;
    if (tid < 128) {
        int pexcl = v - pcnt;
        excls[tid] = pexcl;
        int node = (b << 7) + tid;
        int rb = cbase + pexcl;
        float di = rsqrtf((float)(myc + 1));
        dv[tid] = di;
        if (node < N) {
            rowbeg[node] = rb;
            rowend[node] = rb + 1 + myc;   // EXACT end (pads excluded)
            dinvg[node] = di;
            csr[rb] = (unsigned short)node;   // self entry first
        }
    }
    __syncthreads();
    #pragma unroll
    for (int ii = 0; ii < 16; ++ii) {
        int i = ii * 512 + tid;
        if (i < ne) {
            int nl = (pk[ii] >> 16) & 127;
            csr[cbase + excls[nl] + 1 + rk[ii]] = (unsigned short)(pk[ii] & 0xFFFFu);
        }
    }
    __syncthreads();
    if (tid < 128) {   // fill pad slots with dummy node N (zero row)
        int pexcl = excls[tid];
        for (int p = pexcl + 1 + myc; p < pexcl + pcnt; ++p)
            csr[cbase + p] = (unsigned short)N;
    }
    __syncthreads();
    // scale h rows of this bucket by dinv (fp16 in place): 128 rows x 4 uint4
    uint4* h4 = reinterpret_cast<uint4*>(hh);
    size_t hbase = (size_t)(b << 7) * 4;
    {
        int nl = tid >> 2;
        if (((b << 7) + nl) < N) {
            uint4 vv = h4[hbase + tid];
            float d = dv[nl];
            __half2* hv = reinterpret_cast<__half2*>(&vv);
            #pragma unroll
            for (int t = 0; t < 4; ++t) {
                float2 f = __half22float2(hv[t]);
                hv[t] = __floats2half2_rn(f.x * d, f.y * d);
            }
            h4[hbase + tid] = vv;
        }
    }
}

// fp16 -> fp32 accumulate in ONE instruction per feature: v_fma_mix_f32
#define MIXLO(ACC, U) asm("v_fma_mix_f32 %0, %1, 1.0, %0 op_sel:[0,0,0] op_sel_hi:[1,0,0]" : "+v"(ACC) : "v"(U))
#define MIXHI(ACC, U) asm("v_fma_mix_f32 %0, %1, 1.0, %0 op_sel:[1,0,0] op_sel_hi:[1,0,0]" : "+v"(ACC) : "v"(U))
#define ACC8M(A, V) do {            \
    MIXLO((A)[0], (V).x); MIXHI((A)[1], (V).x); \
    MIXLO((A)[2], (V).y); MIXHI((A)[3], (V).y); \
    MIXLO((A)[4], (V).z); MIXHI((A)[5], (V).z); \
    MIXLO((A)[6], (V).w); MIXHI((A)[7], (V).w); \
} while (0)

// Gather loop: 8 entries/iter; csr indices read NON-TEMPORALLY (single-touch,
// full-line 16B sequential stream) so the 3.2MB hp table keeps L2 residency.
#define AGG_GATHER_LOOP(beg_, endx_, h_)                                      \
    int t = (beg_) + 8 * (h_);                                                \
    if (t < (endx_)) {                                                        \
        u32x4 c4 = __builtin_nontemporal_load(                                \
            reinterpret_cast<const u32x4*>(csr + t));                         \
        while (t < (endx_)) {                                                 \
            int tn = t + 16;                                                  \
            int tc = (tn < (endx_)) ? tn : t;   /* clamp: stay in-bounds */   \
            u32x4 c4n = __builtin_nontemporal_load(                           \
                reinterpret_cast<const u32x4*>(csr + tc));                    \
            unsigned a0 = c4[0] & 0xFFFFu, a1 = c4[0] >> 16;                  \
            unsigned a2 = c4[1] & 0xFFFFu, a3 = c4[1] >> 16;                  \
            unsigned a4 = c4[2] & 0xFFFFu, a5 = c4[2] >> 16;                  \
            unsigned a6 = c4[3] & 0xFFFFu, a7 = c4[3] >> 16;                  \
            uint4 v0 = hp4[(size_t)a0 * 4 + q];                               \
            uint4 v1 = hp4[(size_t)a1 * 4 + q];                               \
            uint4 v2 = hp4[(size_t)a2 * 4 + q];                               \
            uint4 v3 = hp4[(size_t)a3 * 4 + q];                               \
            uint4 v4 = hp4[(size_t)a4 * 4 + q];                               \
            uint4 v5 = hp4[(size_t)a5 * 4 + q];                               \
            uint4 v6 = hp4[(size_t)a6 * 4 + q];                               \
            uint4 v7 = hp4[(size_t)a7 * 4 + q];                               \
            ACC8M(acc, v0); ACC8M(accB, v1); ACC8M(acc, v2); ACC8M(accB, v3); \
            ACC8M(acc, v4); ACC8M(accB, v5); ACC8M(acc, v6); ACC8M(accB, v7); \
            c4 = c4n;                                                         \
            t = tn;                                                           \
        }                                                                     \
    }

// Two-phase partial combine (h=0 writes, h=1 adds): no LDS atomics.
#define AGG_COMBINE()                                                         \
    if (h == 0) {                                                             \
        _Pragma("unroll")                                                     \
        for (int j2 = 0; j2 < 8; ++j2)                                        \
            aggT[q * 8 + j2][node_loc] = acc[j2] + accB[j2];                  \
    }                                                                         \
    __syncthreads();                                                          \
    if (h == 1) {                                                             \
        _Pragma("unroll")                                                     \
        for (int j2 = 0; j2 < 8; ++j2)                                        \
            aggT[q * 8 + j2][node_loc] += acc[j2] + accB[j2];                 \
    }                                                                         \
    __syncthreads();

// agg layer1 + bias + relu + gemm2 + dinv pre-scale.
__global__ __launch_bounds__(256)
void k_aggmm1(const __half* __restrict__ hp, const int* __restrict__ rowbeg,
              const int* __restrict__ rowend, const unsigned short* __restrict__ csr,
              const float* __restrict__ dinv, const float* __restrict__ b1,
              const float* __restrict__ W2, __half* __restrict__ hp2, int N) {
    __shared__ float aggT[32][33];    // [feature][node], pitch 33
    __shared__ float W2sh[32 * 32];   // 4 KB
    int tid = threadIdx.x;
    int lane = tid & 63;
    int w = tid >> 6;
    int g = lane >> 2, q = lane & 3;
    int h = w & 1;                    // row-split half (8-entry blocks interleaved)
    int node_loc = (w >> 1) * 16 + g; // 0..31
    int node = (int)blockIdx.x * 32 + node_loc;

    for (int i = tid; i < 256; i += 256)
        reinterpret_cast<float4*>(W2sh)[i] = reinterpret_cast<const float4*>(W2)[i];

    float acc[8], accB[8];
    #pragma unroll
    for (int t = 0; t < 8; ++t) { acc[t] = 0.f; accB[t] = 0.f; }
    int beg = 0, endx = 0;
    if (node < N) { beg = rowbeg[node]; endx = rowend[node]; }
    const uint4* hp4 = reinterpret_cast<const uint4*>(hp);
    AGG_GATHER_LOOP(beg, endx, h)
    AGG_COMBINE()

    // epilogue: 8 threads/node, 4 outcols each
    int nl2 = tid >> 3;               // 0..31
    int cgrp = tid & 7;               // cols cgrp*4..+3
    int onode = (int)blockIdx.x * 32 + nl2;
    float dd = (onode < N) ? dinv[onode] : 0.f;
    float o0 = 0.f, o1 = 0.f, o2 = 0.f, o3 = 0.f;
    #pragma unroll
    for (int k = 0; k < 32; ++k) {
        float yk = fmaxf(aggT[k][nl2] * dd + b1[k], 0.f);
        float4 wv = *reinterpret_cast<const float4*>(&W2sh[k * 32 + cgrp * 4]);
        o0 += yk * wv.x; o1 += yk * wv.y; o2 += yk * wv.z; o3 += yk * wv.w;
    }
    if (onode <= N) {   // node N: dd=0 -> stores zeros (pad row for layer-2 gathers)
        __half2 pa = __floats2half2_rn(o0 * dd, o1 * dd);
        __half2 pb = __floats2half2_rn(o2 * dd, o3 * dd);
        uint2 st;
        st.x = *reinterpret_cast<unsigned int*>(&pa);
        st.y = *reinterpret_cast<unsigned int*>(&pb);
        *reinterpret_cast<uint2*>(hp2 + (size_t)onode * 32 + cgrp * 4) = st;
    }
}

// agg layer2 + bias + relu + head (64 outcols). Same gather structure.
__global__ __launch_bounds__(256)
void k_aggout(const __half* __restrict__ hp, const int* __restrict__ rowbeg,
              const int* __restrict__ rowend, const unsigned short* __restrict__ csr,
              const float* __restrict__ dinv, const float* __restrict__ b2,
              const float* __restrict__ Wo, const float* __restrict__ bo,
              float* __restrict__ out, int N) {
    __shared__ float aggT[32][33];
    __shared__ float Wosh[32 * 64];   // 8 KB
    int tid = threadIdx.x;
    int lane = tid & 63;
    int w = tid >> 6;
    int g = lane >> 2, q = lane & 3;
    int h = w & 1;
    int node_loc = (w >> 1) * 16 + g;
    int node = (int)blockIdx.x * 32 + node_loc;

    for (int i = tid; i < 512; i += 256)
        reinterpret_cast<float4*>(Wosh)[i] = reinterpret_cast<const float4*>(Wo)[i];

    float acc[8], accB[8];
    #pragma unroll
    for (int t = 0; t < 8; ++t) { acc[t] = 0.f; accB[t] = 0.f; }
    int beg = 0, endx = 0;
    if (node < N) { beg = rowbeg[node]; endx = rowend[node]; }
    const uint4* hp4 = reinterpret_cast<const uint4*>(hp);
    AGG_GATHER_LOOP(beg, endx, h)
    AGG_COMBINE()

    // epilogue: 8 threads/node, 8 outcols each
    int nl2 = tid >> 3;
    int cgrp = tid & 7;               // cols cgrp*8..+7
    int onode = (int)blockIdx.x * 32 + nl2;
    float dd = (onode < N) ? dinv[onode] : 0.f;
    float o[8];
    #pragma unroll
    for (int i = 0; i < 8; ++i) o[i] = 0.f;
    #pragma unroll
    for (int k = 0; k < 32; ++k) {
        float yk = fmaxf(aggT[k][nl2] * dd + b2[k], 0.f);
        float4 wa = *reinterpret_cast<const float4*>(&Wosh[k * 64 + cgrp * 8]);
        float4 wb = *reinterpret_cast<const float4*>(&Wosh[k * 64 + cgrp * 8 + 4]);
        o[0] += yk * wa.x; o[1] += yk * wa.y; o[2] += yk * wa.z; o[3] += yk * wa.w;
        o[4] += yk * wb.x; o[5] += yk * wb.y; o[6] += yk * wb.z; o[7] += yk * wb.w;
    }
    if (onode < N) {
        float4 ba = *reinterpret_cast<const float4*>(bo + cgrp * 8);
        float4 bb = *reinterpret_cast<const float4*>(bo + cgrp * 8 + 4);
        float4 s0 = make_float4(o[0] + ba.x, o[1] + ba.y, o[2] + ba.z, o[3] + ba.w);
        float4 s1 = make_float4(o[4] + bb.x, o[5] + bb.y, o[6] + bb.z, o[7] + bb.w);
        float4* op = reinterpret_cast<float4*>(out + (size_t)onode * 64 + cgrp * 8);
        op[0] = s0;
        op[1] = s1;
    }
}

extern "C" void kernel_launch(void* const* d_in, const int* in_sizes, int n_in,
                              void* d_out, int out_size, void* d_ws, size_t ws_size,
                              hipStream_t stream) {
    const float* x  = (const float*)d_in[0];
    const int*   ei = (const int*)d_in[1];
    const float* W1 = (const float*)d_in[2];
    const float* b1 = (const float*)d_in[3];
    const float* W2 = (const float*)d_in[4];
    const float* b2 = (const float*)d_in[5];
    const float* Wo = (const float*)d_in[6];
    const float* bo = (const float*)d_in[7];
    float* out = (float*)d_out;

    const int N = in_sizes[0] / 128;   // 50000
    const int E = in_sizes[1] / 2;     // 1600000
    const int* src = ei;
    const int* dst = ei + E;

    char* ws = (char*)d_ws;
    size_t off = 0;
    auto alloc = [&](size_t bytes) {
        void* p = ws + off;
        off += (bytes + 255) & ~(size_t)255;
        return p;
    };
    int*            cursor = (int*)           alloc(512 * 4);
    unsigned int*   binned = (unsigned int*)  alloc((size_t)NBUCK * BCAP * 4);
    int*            rowbeg = (int*)           alloc((size_t)N * 4);
    int*            rowend = (int*)           alloc((size_t)N * 4);
    float*          dinv   = (float*)         alloc((size_t)N * 4);
    unsigned short* csr    = (unsigned short*)alloc((size_t)NBUCK * CCAP * 2);
    __half*         bufAh  = (__half*)        alloc((size_t)(N + 1) * 32 * 2);
    __half*         bufBh  = (__half*)        alloc((size_t)(N + 1) * 32 * 2);

    const int nFront = NGEMM * 2;                    // 1568 (odd slots: 782 binA used)
    const int gAgg1  = (N + 1 + 31) / 32;            // covers pad node N
    const int gAgg2  = (N + 31) / 32;

    hipMemsetAsync(cursor, 0, 512 * 4, stream);
    k_front<<<nFront, 256, 0, stream>>>(x, W1, bufAh, N, src, dst, E,
                                        cursor, binned);
    k_binB<<<NBUCK, 512, 0, stream>>>(binned, cursor, rowbeg, rowend, dinv,
                                      csr, bufAh, N);
    k_aggmm1<<<gAgg1, 256, 0, stream>>>(bufAh, rowbeg, rowend, csr, dinv, b1,
                                        W2, bufBh, N);
    k_aggout<<<gAgg2, 256, 0, stream>>>(bufBh, rowbeg, rowend, csr, dinv, b2,
                                        Wo, bo, out, N);
}

// Round 14
// 162.529 us; speedup vs baseline: 1.0464x; 1.0464x over previous
//
#include <hip/hip_runtime.h>
#include <hip/hip_fp16.h>

#define CHUNK 8192        // edges per binA block (512 threads x 16) -- r14: halves cursor atomics
#define NBUCK 391         // buckets of 128 nodes (dst>>7)
#define BCAP  8192        // per-bucket edge capacity (mean 4096, 64 sigma slack)
#define CCAP  (BCAP+2048) // csr region capacity (edges + self + per-row pad to x8)
#define NGEMM 196         // gemm tiles of 256 rows (covers N+1 = 50001)

using u32x4 = __attribute__((ext_vector_type(4))) unsigned int;

// L2-hygiene policy (r8/r10/r11 causal triple): nt ONLY on single-touch,
// full-line streams (csr reads in aggs: +30us win, r10). nt on reused data
// (r8: +16us) or on line-reused/partial-line accesses (r11: +27us) REGRESSES.
// Front-atomic theory (r14): binA's global cursor atomics (blocks x 512) are
// the front limiter; CHUNK 8192 halves them vs 4096.

union FrontSmem {
    struct { float Wsh[128 * 32]; } g;                       // 16 KB
    struct { int cnt[512]; int lbase[512]; int gbs[512]; int wsum[8];
             unsigned int stage[CHUNK]; } a;                 // 38.2 KB
};

__global__ __launch_bounds__(512)
void k_front(const float* __restrict__ x, const float* __restrict__ W,
             __half* __restrict__ h, int N,
             const int* __restrict__ src, const int* __restrict__ dst, int E,
             int* __restrict__ cursor, unsigned int* __restrict__ binned) {
    __shared__ FrontSmem sm;
    int bid = (int)blockIdx.x;
    int tid = threadIdx.x;
    bool isg = (bid & 1) == 0;        // even bids: 196 gemm tiles

    if (isg) {
        // ---- gemm path: 256 rows/block; thread = 1 row x 16 cols (2 thr/row)
        float* Wsh = sm.g.Wsh;
        for (int j = tid; j < 1024; j += 512)
            reinterpret_cast<float4*>(Wsh)[j] = reinterpret_cast<const float4*>(W)[j];
        __syncthreads();
        int r = tid & 255;            // row in tile
        int ch = tid >> 8;            // col half: cols ch*16 .. ch*16+15
        int row = (bid >> 1) * 256 + r;
        const float4 z4 = make_float4(0.f, 0.f, 0.f, 0.f);
        float4 acc4[4];
        #pragma unroll
        for (int c = 0; c < 4; ++c) acc4[c] = z4;
        if (row < N) {
            const float4* xr = reinterpret_cast<const float4*>(x + (size_t)row * 128);
            float4 bufA[4], bufB[4];
            #pragma unroll
            for (int i = 0; i < 4; ++i) bufA[i] = xr[i];
            #pragma unroll
            for (int blk = 0; blk < 8; ++blk) {
                if (blk < 7) {
                    if ((blk & 1) == 0) {
                        #pragma unroll
                        for (int i = 0; i < 4; ++i) bufB[i] = xr[(blk + 1) * 4 + i];
                    } else {
                        #pragma unroll
                        for (int i = 0; i < 4; ++i) bufA[i] = xr[(blk + 1) * 4 + i];
                    }
                }
                #pragma unroll
                for (int i = 0; i < 4; ++i) {
                    float4 xv = ((blk & 1) == 0) ? bufA[i] : bufB[i];
                    const float* xp = reinterpret_cast<const float*>(&xv);
                    #pragma unroll
                    for (int j = 0; j < 4; ++j) {
                        float xj = xp[j];
                        const float4* wr = reinterpret_cast<const float4*>(
                            Wsh + ((blk * 4 + i) * 4 + j) * 32 + ch * 16);
                        #pragma unroll
                        for (int c = 0; c < 4; ++c) {
                            float4 wv = wr[c];   // wave-uniform LDS -> broadcast
                            acc4[c].x += xj * wv.x; acc4[c].y += xj * wv.y;
                            acc4[c].z += xj * wv.z; acc4[c].w += xj * wv.w;
                        }
                    }
                }
            }
        }
        if (row <= N) {   // row N (pad): acc stays zero -> zero row
            __half2 h0 = __floats2half2_rn(acc4[0].x, acc4[0].y);
            __half2 h1 = __floats2half2_rn(acc4[0].z, acc4[0].w);
            __half2 h2 = __floats2half2_rn(acc4[1].x, acc4[1].y);
            __half2 h3 = __floats2half2_rn(acc4[1].z, acc4[1].w);
            __half2 h4 = __floats2half2_rn(acc4[2].x, acc4[2].y);
            __half2 h5 = __floats2half2_rn(acc4[2].z, acc4[2].w);
            __half2 h6 = __floats2half2_rn(acc4[3].x, acc4[3].y);
            __half2 h7 = __floats2half2_rn(acc4[3].z, acc4[3].w);
            uint4 s0, s1;
            s0.x = *reinterpret_cast<unsigned int*>(&h0);
            s0.y = *reinterpret_cast<unsigned int*>(&h1);
            s0.z = *reinterpret_cast<unsigned int*>(&h2);
            s0.w = *reinterpret_cast<unsigned int*>(&h3);
            s1.x = *reinterpret_cast<unsigned int*>(&h4);
            s1.y = *reinterpret_cast<unsigned int*>(&h5);
            s1.z = *reinterpret_cast<unsigned int*>(&h6);
            s1.w = *reinterpret_cast<unsigned int*>(&h7);
            uint4* op = reinterpret_cast<uint4*>(h + (size_t)row * 32 + ch * 16);
            op[0] = s0;
            op[1] = s1;
        }
        return;
    }

    // ---- binA path: rank -> wave-shfl scan -> LDS stage -> run writes
    int abid = bid >> 1;              // odd bids: 196 blocks, all used
    if (abid * CHUNK >= E) return;
    int* cnt = sm.a.cnt;
    int* lbase = sm.a.lbase;
    int* gbs = sm.a.gbs;
    unsigned int* stage = sm.a.stage;
    cnt[tid] = 0;
    __syncthreads();
    int base = abid * CHUNK;
    unsigned int pk[16];
    int rk[16];
    unsigned int mask = 0;
    #pragma unroll
    for (int i = 0; i < 4; ++i) {
        int e = base + i * 2048 + tid * 4;
        if (e + 3 < E) {
            int4 d4 = *reinterpret_cast<const int4*>(dst + e);
            int4 s4 = *reinterpret_cast<const int4*>(src + e);
            pk[i*4+0] = ((unsigned)d4.x << 16) | (unsigned)s4.x; rk[i*4+0] = atomicAdd(&cnt[d4.x >> 7], 1);
            pk[i*4+1] = ((unsigned)d4.y << 16) | (unsigned)s4.y; rk[i*4+1] = atomicAdd(&cnt[d4.y >> 7], 1);
            pk[i*4+2] = ((unsigned)d4.z << 16) | (unsigned)s4.z; rk[i*4+2] = atomicAdd(&cnt[d4.z >> 7], 1);
            pk[i*4+3] = ((unsigned)d4.w << 16) | (unsigned)s4.w; rk[i*4+3] = atomicAdd(&cnt[d4.w >> 7], 1);
            mask |= 0xFu << (i * 4);
        } else {
            for (int j = 0; j < 4; ++j) {
                int k = e + j;
                if (k < E) {
                    int d = dst[k], s = src[k];
                    pk[i*4+j] = ((unsigned)d << 16) | (unsigned)s;
                    rk[i*4+j] = atomicAdd(&cnt[d >> 7], 1);
                    mask |= 1u << (i * 4 + j);
                }
            }
        }
    }
    __syncthreads();
    int myc = cnt[tid];
    int lid = tid & 63, wid = tid >> 6;
    int v = myc;
    #pragma unroll
    for (int d = 1; d < 64; d <<= 1) {
        int u = __shfl_up(v, d, 64);
        if (lid >= d) v += u;
    }
    if (lid == 63) sm.a.wsum[wid] = v;
    __syncthreads();
    int pre = 0, tot = 0;
    #pragma unroll
    for (int w2 = 0; w2 < 8; ++w2) {
        int s = sm.a.wsum[w2];
        tot += s;
        if (w2 < wid) pre += s;
    }
    int inc = v + pre;                 // global inclusive prefix
    lbase[tid] = inc - myc;
    gbs[tid] = myc ? atomicAdd(&cursor[tid], myc) : 0;
    int nvalid = tot;
    __syncthreads();
    #pragma unroll
    for (int i = 0; i < 16; ++i) {
        if (mask & (1u << i)) {
            int b = pk[i] >> 23;
            stage[lbase[b] + rk[i]] = pk[i];
        }
    }
    __syncthreads();
    for (int i = tid; i < nvalid; i += 512) {
        unsigned int v2 = stage[i];
        int b = v2 >> 23;
        binned[(size_t)b * BCAP + gbs[b] + (i - lbase[b])] = v2;   // regular: binB reuses
    }
}

// binB: one block per 128-node bucket. Single pass with rank recording.
__global__ __launch_bounds__(512)
void k_binB(const unsigned int* __restrict__ binned, const int* __restrict__ cursor,
            int* __restrict__ rowbeg, int* __restrict__ rowend, float* __restrict__ dinvg,
            unsigned short* __restrict__ csr, __half* __restrict__ hh, int N) {
    __shared__ int cnt[128];
    __shared__ int excls[128];
    __shared__ float dv[128];
    __shared__ int wsum2[2];
    int tid = threadIdx.x;
    int b = blockIdx.x;
    size_t ebase = (size_t)b * BCAP;
    int ne = cursor[b];
    if (tid < 128) cnt[tid] = 0;
    __syncthreads();
    unsigned int pk[16];
    int rk[16];
    #pragma unroll
    for (int ii = 0; ii < 16; ++ii) {
        int i = ii * 512 + tid;
        if (i < ne) {
            pk[ii] = binned[ebase + i];
            rk[ii] = atomicAdd(&cnt[(pk[ii] >> 16) & 127], 1);
        }
    }
    __syncthreads();
    int myc = 0, pcnt = 0;
    if (tid < 128) {
        myc = cnt[tid];
        pcnt = (myc + 1 + 7) & ~7;   // self + edges, padded to x8 (region layout)
    }
    int lid = tid & 63, wid2 = tid >> 6;
    int v = pcnt;
    if (tid < 128) {
        #pragma unroll
        for (int d = 1; d < 64; d <<= 1) {
            int u = __shfl_up(v, d, 64);
            if (lid >= d) v += u;
        }
        if (lid == 63) wsum2[wid2] = v;
    }
    __syncthreads();
    if (tid < 128 && wid2 == 1) v += wsum2[0];
    int cbase = b * CCAP;
    if (tid < 128) {
        int pexcl = v - pcnt;
        excls[tid] = pexcl;
        int node = (b << 7) + tid;
        int rb = cbase + pexcl;
        float di = rsqrtf((float)(myc + 1));
        dv[tid] = di;
        if (node < N) {
            rowbeg[node] = rb;
            rowend[node] = rb + 1 + myc;   // EXACT end (pads excluded)
            dinvg[node] = di;
            csr[rb] = (unsigned short)node;   // self entry first
        }
    }
    __syncthreads();
    #pragma unroll
    for (int ii = 0; ii < 16; ++ii) {
        int i = ii * 512 + tid;
        if (i < ne) {
            int nl = (pk[ii] >> 16) & 127;
            csr[cbase + excls[nl] + 1 + rk[ii]] = (unsigned short)(pk[ii] & 0xFFFFu);
        }
    }
    __syncthreads();
    if (tid < 128) {   // fill pad slots with dummy node N (zero row)
        int pexcl = excls[tid];
        for (int p = pexcl + 1 + myc; p < pexcl + pcnt; ++p)
            csr[cbase + p] = (unsigned short)N;
    }
    __syncthreads();
    // scale h rows of this bucket by dinv (fp16 in place): 128 rows x 4 uint4
    uint4* h4 = reinterpret_cast<uint4*>(hh);
    size_t hbase = (size_t)(b << 7) * 4;
    {
        int nl = tid >> 2;
        if (((b << 7) + nl) < N) {
            uint4 vv = h4[hbase + tid];
            float d = dv[nl];
            __half2* hv = reinterpret_cast<__half2*>(&vv);
            #pragma unroll
            for (int t = 0; t < 4; ++t) {
                float2 f = __half22float2(hv[t]);
                hv[t] = __floats2half2_rn(f.x * d, f.y * d);
            }
            h4[hbase + tid] = vv;
        }
    }
}

// fp16 -> fp32 accumulate in ONE instruction per feature: v_fma_mix_f32
#define MIXLO(ACC, U) asm("v_fma_mix_f32 %0, %1, 1.0, %0 op_sel:[0,0,0] op_sel_hi:[1,0,0]" : "+v"(ACC) : "v"(U))
#define MIXHI(ACC, U) asm("v_fma_mix_f32 %0, %1, 1.0, %0 op_sel:[1,0,0] op_sel_hi:[1,0,0]" : "+v"(ACC) : "v"(U))
#define ACC8M(A, V) do {            \
    MIXLO((A)[0], (V).x); MIXHI((A)[1], (V).x); \
    MIXLO((A)[2], (V).y); MIXHI((A)[3], (V).y); \
    MIXLO((A)[4], (V).z); MIXHI((A)[5], (V).z); \
    MIXLO((A)[6], (V).w); MIXHI((A)[7], (V).w); \
} while (0)

// Gather loop: 8 entries/iter; csr indices read NON-TEMPORALLY (single-touch,
// full-line 16B sequential stream) so the 3.2MB hp table keeps L2 residency.
#define AGG_GATHER_LOOP(beg_, endx_, h_)                                      \
    int t = (beg_) + 8 * (h_);                                                \
    if (t < (endx_)) {                                                        \
        u32x4 c4 = __builtin_nontemporal_load(                                \
            reinterpret_cast<const u32x4*>(csr + t));                         \
        while (t < (endx_)) {                                                 \
            int tn = t + 16;                                                  \
            int tc = (tn < (endx_)) ? tn : t;   /* clamp: stay in-bounds */   \
            u32x4 c4n = __builtin_nontemporal_load(                           \
                reinterpret_cast<const u32x4*>(csr + tc));                    \
            unsigned a0 = c4[0] & 0xFFFFu, a1 = c4[0] >> 16;                  \
            unsigned a2 = c4[1] & 0xFFFFu, a3 = c4[1] >> 16;                  \
            unsigned a4 = c4[2] & 0xFFFFu, a5 = c4[2] >> 16;                  \
            unsigned a6 = c4[3] & 0xFFFFu, a7 = c4[3] >> 16;                  \
            uint4 v0 = hp4[(size_t)a0 * 4 + q];                               \
            uint4 v1 = hp4[(size_t)a1 * 4 + q];                               \
            uint4 v2 = hp4[(size_t)a2 * 4 + q];                               \
            uint4 v3 = hp4[(size_t)a3 * 4 + q];                               \
            uint4 v4 = hp4[(size_t)a4 * 4 + q];                               \
            uint4 v5 = hp4[(size_t)a5 * 4 + q];                               \
            uint4 v6 = hp4[(size_t)a6 * 4 + q];                               \
            uint4 v7 = hp4[(size_t)a7 * 4 + q];                               \
            ACC8M(acc, v0); ACC8M(accB, v1); ACC8M(acc, v2); ACC8M(accB, v3); \
            ACC8M(acc, v4); ACC8M(accB, v5); ACC8M(acc, v6); ACC8M(accB, v7); \
            c4 = c4n;                                                         \
            t = tn;                                                           \
        }                                                                     \
    }

// Two-phase partial combine (h=0 writes, h=1 adds): no LDS atomics.
#define AGG_COMBINE()                                                         \
    if (h == 0) {                                                             \
        _Pragma("unroll")                                                     \
        for (int j2 = 0; j2 < 8; ++j2)                                        \
            aggT[q * 8 + j2][node_loc] = acc[j2] + accB[j2];                  \
    }                                                                         \
    __syncthreads();                                                          \
    if (h == 1) {                                                             \
        _Pragma("unroll")                                                     \
        for (int j2 = 0; j2 < 8; ++j2)                                        \
            aggT[q * 8 + j2][node_loc] += acc[j2] + accB[j2];                 \
    }                                                                         \
    __syncthreads();

// agg layer1 + bias + relu + gemm2 + dinv pre-scale.
__global__ __launch_bounds__(256)
void k_aggmm1(const __half* __restrict__ hp, const int* __restrict__ rowbeg,
              const int* __restrict__ rowend, const unsigned short* __restrict__ csr,
              const float* __restrict__ dinv, const float* __restrict__ b1,
              const float* __restrict__ W2, __half* __restrict__ hp2, int N) {
    __shared__ float aggT[32][33];    // [feature][node], pitch 33
    __shared__ float W2sh[32 * 32];   // 4 KB
    int tid = threadIdx.x;
    int lane = tid & 63;
    int w = tid >> 6;
    int g = lane >> 2, q = lane & 3;
    int h = w & 1;                    // row-split half (8-entry blocks interleaved)
    int node_loc = (w >> 1) * 16 + g; // 0..31
    int node = (int)blockIdx.x * 32 + node_loc;

    for (int i = tid; i < 256; i += 256)
        reinterpret_cast<float4*>(W2sh)[i] = reinterpret_cast<const float4*>(W2)[i];

    float acc[8], accB[8];
    #pragma unroll
    for (int t = 0; t < 8; ++t) { acc[t] = 0.f; accB[t] = 0.f; }
    int beg = 0, endx = 0;
    if (node < N) { beg = rowbeg[node]; endx = rowend[node]; }
    const uint4* hp4 = reinterpret_cast<const uint4*>(hp);
    AGG_GATHER_LOOP(beg, endx, h)
    AGG_COMBINE()

    // epilogue: 8 threads/node, 4 outcols each
    int nl2 = tid >> 3;               // 0..31
    int cgrp = tid & 7;               // cols cgrp*4..+3
    int onode = (int)blockIdx.x * 32 + nl2;
    float dd = (onode < N) ? dinv[onode] : 0.f;
    float o0 = 0.f, o1 = 0.f, o2 = 0.f, o3 = 0.f;
    #pragma unroll
    for (int k = 0; k < 32; ++k) {
        float yk = fmaxf(aggT[k][nl2] * dd + b1[k], 0.f);
        float4 wv = *reinterpret_cast<const float4*>(&W2sh[k * 32 + cgrp * 4]);
        o0 += yk * wv.x; o1 += yk * wv.y; o2 += yk * wv.z; o3 += yk * wv.w;
    }
    if (onode <= N) {   // node N: dd=0 -> stores zeros (pad row for layer-2 gathers)
        __half2 pa = __floats2half2_rn(o0 * dd, o1 * dd);
        __half2 pb = __floats2half2_rn(o2 * dd, o3 * dd);
        uint2 st;
        st.x = *reinterpret_cast<unsigned int*>(&pa);
        st.y = *reinterpret_cast<unsigned int*>(&pb);
        *reinterpret_cast<uint2*>(hp2 + (size_t)onode * 32 + cgrp * 4) = st;
    }
}

// agg layer2 + bias + relu + head (64 outcols). Same gather structure.
__global__ __launch_bounds__(256)
void k_aggout(const __half* __restrict__ hp, const int* __restrict__ rowbeg,
              const int* __restrict__ rowend, const unsigned short* __restrict__ csr,
              const float* __restrict__ dinv, const float* __restrict__ b2,
              const float* __restrict__ Wo, const float* __restrict__ bo,
              float* __restrict__ out, int N) {
    __shared__ float aggT[32][33];
    __shared__ float Wosh[32 * 64];   // 8 KB
    int tid = threadIdx.x;
    int lane = tid & 63;
    int w = tid >> 6;
    int g = lane >> 2, q = lane & 3;
    int h = w & 1;
    int node_loc = (w >> 1) * 16 + g;
    int node = (int)blockIdx.x * 32 + node_loc;

    for (int i = tid; i < 512; i += 256)
        reinterpret_cast<float4*>(Wosh)[i] = reinterpret_cast<const float4*>(Wo)[i];

    float acc[8], accB[8];
    #pragma unroll
    for (int t = 0; t < 8; ++t) { acc[t] = 0.f; accB[t] = 0.f; }
    int beg = 0, endx = 0;
    if (node < N) { beg = rowbeg[node]; endx = rowend[node]; }
    const uint4* hp4 = reinterpret_cast<const uint4*>(hp);
    AGG_GATHER_LOOP(beg, endx, h)
    AGG_COMBINE()

    // epilogue: 8 threads/node, 8 outcols each
    int nl2 = tid >> 3;
    int cgrp = tid & 7;               // cols cgrp*8..+7
    int onode = (int)blockIdx.x * 32 + nl2;
    float dd = (onode < N) ? dinv[onode] : 0.f;
    float o[8];
    #pragma unroll
    for (int i = 0; i < 8; ++i) o[i] = 0.f;
    #pragma unroll
    for (int k = 0; k < 32; ++k) {
        float yk = fmaxf(aggT[k][nl2] * dd + b2[k], 0.f);
        float4 wa = *reinterpret_cast<const float4*>(&Wosh[k * 64 + cgrp * 8]);
        float4 wb = *reinterpret_cast<const float4*>(&Wosh[k * 64 + cgrp * 8 + 4]);
        o[0] += yk * wa.x; o[1] += yk * wa.y; o[2] += yk * wa.z; o[3] += yk * wa.w;
        o[4] += yk * wb.x; o[5] += yk * wb.y; o[6] += yk * wb.z; o[7] += yk * wb.w;
    }
    if (onode < N) {
        float4 ba = *reinterpret_cast<const float4*>(bo + cgrp * 8);
        float4 bb = *reinterpret_cast<const float4*>(bo + cgrp * 8 + 4);
        float4 s0 = make_float4(o[0] + ba.x, o[1] + ba.y, o[2] + ba.z, o[3] + ba.w);
        float4 s1 = make_float4(o[4] + bb.x, o[5] + bb.y, o[6] + bb.z, o[7] + bb.w);
        float4* op = reinterpret_cast<float4*>(out + (size_t)onode * 64 + cgrp * 8);
        op[0] = s0;
        op[1] = s1;
    }
}

extern "C" void kernel_launch(void* const* d_in, const int* in_sizes, int n_in,
                              void* d_out, int out_size, void* d_ws, size_t ws_size,
                              hipStream_t stream) {
    const float* x  = (const float*)d_in[0];
    const int*   ei = (const int*)d_in[1];
    const float* W1 = (const float*)d_in[2];
    const float* b1 = (const float*)d_in[3];
    const float* W2 = (const float*)d_in[4];
    const float* b2 = (const float*)d_in[5];
    const float* Wo = (const float*)d_in[6];
    const float* bo = (const float*)d_in[7];
    float* out = (float*)d_out;

    const int N = in_sizes[0] / 128;   // 50000
    const int E = in_sizes[1] / 2;     // 1600000
    const int* src = ei;
    const int* dst = ei + E;

    char* ws = (char*)d_ws;
    size_t off = 0;
    auto alloc = [&](size_t bytes) {
        void* p = ws + off;
        off += (bytes + 255) & ~(size_t)255;
        return p;
    };
    int*            cursor = (int*)           alloc(512 * 4);
    unsigned int*   binned = (unsigned int*)  alloc((size_t)NBUCK * BCAP * 4);
    int*            rowbeg = (int*)           alloc((size_t)N * 4);
    int*            rowend = (int*)           alloc((size_t)N * 4);
    float*          dinv   = (float*)         alloc((size_t)N * 4);
    unsigned short* csr    = (unsigned short*)alloc((size_t)NBUCK * CCAP * 2);
    __half*         bufAh  = (__half*)        alloc((size_t)(N + 1) * 32 * 2);
    __half*         bufBh  = (__half*)        alloc((size_t)(N + 1) * 32 * 2);

    const int nFront = NGEMM * 2;                    // 392 (even gemm, odd binA)
    const int gAgg1  = (N + 1 + 31) / 32;            // covers pad node N
    const int gAgg2  = (N + 31) / 32;

    hipMemsetAsync(cursor, 0, 512 * 4, stream);
    k_front<<<nFront, 512, 0, stream>>>(x, W1, bufAh, N, src, dst, E,
                                        cursor, binned);
    k_binB<<<NBUCK, 512, 0, stream>>>(binned, cursor, rowbeg, rowend, dinv,
                                      csr, bufAh, N);
    k_aggmm1<<<gAgg1, 256, 0, stream>>>(bufAh, rowbeg, rowend, csr, dinv, b1,
                                        W2, bufBh, N);
    k_aggout<<<gAgg2, 256, 0, stream>>>(bufBh, rowbeg, rowend, csr, dinv, b2,
                                        Wo, bo, out, N);
}

// Round 15
// 158.909 us; speedup vs baseline: 1.0702x; 1.0228x over previous
//
#include <hip/hip_runtime.h>
#include <hip/hip_fp16.h>

#define CHUNK 4096        // edges per binA block
#define NBUCK 391         // buckets of 128 nodes (dst>>7)
#define BCAP  8192        // per-bucket edge capacity (mean 4096, 64 sigma slack)
#define CCAP  (BCAP+2048) // csr region capacity (edges + self + per-row pad to x8)
#define NGEMM 196         // gemm tiles of 256 rows (covers N+1 = 50001)

using u32x4 = __attribute__((ext_vector_type(4))) unsigned int;

// L2-hygiene policy (r8/r10/r11 causal triple): nt ONLY on single-touch,
// full-line streams (csr reads in aggs: +30us win, r10). nt on reused data
// (r8: +16us) or on line-reused/partial-line accesses (r11: x row chunks,
// 2B csr scatter stores -> +27us) REGRESSES. Everything else stays regular.
// Front theories falsified (r5/r12/r13/r14): TLP, chain length, chunk size,
// cursor atomics -- this is the locked 160.9us configuration.

union FrontSmem {
    struct { float Wsh[128 * 32]; } g;                       // 16 KB
    struct { int cnt[512]; int lbase[512]; int gbs[512]; int wsum[8];
             unsigned int stage[CHUNK]; } a;                 // 22.6 KB
};

__global__ __launch_bounds__(512)
void k_front(const float* __restrict__ x, const float* __restrict__ W,
             __half* __restrict__ h, int N,
             const int* __restrict__ src, const int* __restrict__ dst, int E,
             int* __restrict__ cursor, unsigned int* __restrict__ binned) {
    __shared__ FrontSmem sm;
    int bid = (int)blockIdx.x;
    int tid = threadIdx.x;
    bool isg = (bid % 3 == 0);        // bids 0,3,...,585 -> exactly 196 blocks

    if (isg) {
        // ---- gemm path: 256 rows/block; thread = 1 row x 16 cols (2 thr/row)
        float* Wsh = sm.g.Wsh;
        for (int j = tid; j < 1024; j += 512)
            reinterpret_cast<float4*>(Wsh)[j] = reinterpret_cast<const float4*>(W)[j];
        __syncthreads();
        int r = tid & 255;            // row in tile
        int ch = tid >> 8;            // col half: cols ch*16 .. ch*16+15
        int row = (bid / 3) * 256 + r;
        const float4 z4 = make_float4(0.f, 0.f, 0.f, 0.f);
        float4 acc4[4];
        #pragma unroll
        for (int c = 0; c < 4; ++c) acc4[c] = z4;
        if (row < N) {
            const float4* xr = reinterpret_cast<const float4*>(x + (size_t)row * 128);
            float4 bufA[4], bufB[4];
            #pragma unroll
            for (int i = 0; i < 4; ++i) bufA[i] = xr[i];
            #pragma unroll
            for (int blk = 0; blk < 8; ++blk) {
                if (blk < 7) {
                    if ((blk & 1) == 0) {
                        #pragma unroll
                        for (int i = 0; i < 4; ++i) bufB[i] = xr[(blk + 1) * 4 + i];
                    } else {
                        #pragma unroll
                        for (int i = 0; i < 4; ++i) bufA[i] = xr[(blk + 1) * 4 + i];
                    }
                }
                #pragma unroll
                for (int i = 0; i < 4; ++i) {
                    float4 xv = ((blk & 1) == 0) ? bufA[i] : bufB[i];
                    const float* xp = reinterpret_cast<const float*>(&xv);
                    #pragma unroll
                    for (int j = 0; j < 4; ++j) {
                        float xj = xp[j];
                        const float4* wr = reinterpret_cast<const float4*>(
                            Wsh + ((blk * 4 + i) * 4 + j) * 32 + ch * 16);
                        #pragma unroll
                        for (int c = 0; c < 4; ++c) {
                            float4 wv = wr[c];   // wave-uniform LDS -> broadcast
                            acc4[c].x += xj * wv.x; acc4[c].y += xj * wv.y;
                            acc4[c].z += xj * wv.z; acc4[c].w += xj * wv.w;
                        }
                    }
                }
            }
        }
        if (row <= N) {   // row N (pad): acc stays zero -> zero row
            __half2 h0 = __floats2half2_rn(acc4[0].x, acc4[0].y);
            __half2 h1 = __floats2half2_rn(acc4[0].z, acc4[0].w);
            __half2 h2 = __floats2half2_rn(acc4[1].x, acc4[1].y);
            __half2 h3 = __floats2half2_rn(acc4[1].z, acc4[1].w);
            __half2 h4 = __floats2half2_rn(acc4[2].x, acc4[2].y);
            __half2 h5 = __floats2half2_rn(acc4[2].z, acc4[2].w);
            __half2 h6 = __floats2half2_rn(acc4[3].x, acc4[3].y);
            __half2 h7 = __floats2half2_rn(acc4[3].z, acc4[3].w);
            uint4 s0, s1;
            s0.x = *reinterpret_cast<unsigned int*>(&h0);
            s0.y = *reinterpret_cast<unsigned int*>(&h1);
            s0.z = *reinterpret_cast<unsigned int*>(&h2);
            s0.w = *reinterpret_cast<unsigned int*>(&h3);
            s1.x = *reinterpret_cast<unsigned int*>(&h4);
            s1.y = *reinterpret_cast<unsigned int*>(&h5);
            s1.z = *reinterpret_cast<unsigned int*>(&h6);
            s1.w = *reinterpret_cast<unsigned int*>(&h7);
            uint4* op = reinterpret_cast<uint4*>(h + (size_t)row * 32 + ch * 16);
            op[0] = s0;
            op[1] = s1;
        }
        return;
    }

    // ---- binA path: rank -> wave-shfl scan -> LDS stage -> run writes
    int abid = bid - (bid / 3 + 1);   // binA index among non-%3 blocks
    int* cnt = sm.a.cnt;
    int* lbase = sm.a.lbase;
    int* gbs = sm.a.gbs;
    unsigned int* stage = sm.a.stage;
    cnt[tid] = 0;
    __syncthreads();
    int base = abid * CHUNK;
    unsigned int pk[8];
    int rk[8];
    unsigned int mask = 0;
    #pragma unroll
    for (int i = 0; i < 2; ++i) {
        int e = base + i * 2048 + tid * 4;
        if (e + 3 < E) {
            int4 d4 = *reinterpret_cast<const int4*>(dst + e);
            int4 s4 = *reinterpret_cast<const int4*>(src + e);
            pk[i*4+0] = ((unsigned)d4.x << 16) | (unsigned)s4.x; rk[i*4+0] = atomicAdd(&cnt[d4.x >> 7], 1);
            pk[i*4+1] = ((unsigned)d4.y << 16) | (unsigned)s4.y; rk[i*4+1] = atomicAdd(&cnt[d4.y >> 7], 1);
            pk[i*4+2] = ((unsigned)d4.z << 16) | (unsigned)s4.z; rk[i*4+2] = atomicAdd(&cnt[d4.z >> 7], 1);
            pk[i*4+3] = ((unsigned)d4.w << 16) | (unsigned)s4.w; rk[i*4+3] = atomicAdd(&cnt[d4.w >> 7], 1);
            mask |= 0xFu << (i * 4);
        } else {
            for (int j = 0; j < 4; ++j) {
                int k = e + j;
                if (k < E) {
                    int d = dst[k], s = src[k];
                    pk[i*4+j] = ((unsigned)d << 16) | (unsigned)s;
                    rk[i*4+j] = atomicAdd(&cnt[d >> 7], 1);
                    mask |= 1u << (i * 4 + j);
                }
            }
        }
    }
    __syncthreads();
    int myc = cnt[tid];
    int lid = tid & 63, wid = tid >> 6;
    int v = myc;
    #pragma unroll
    for (int d = 1; d < 64; d <<= 1) {
        int u = __shfl_up(v, d, 64);
        if (lid >= d) v += u;
    }
    if (lid == 63) sm.a.wsum[wid] = v;
    __syncthreads();
    int pre = 0, tot = 0;
    #pragma unroll
    for (int w2 = 0; w2 < 8; ++w2) {
        int s = sm.a.wsum[w2];
        tot += s;
        if (w2 < wid) pre += s;
    }
    int inc = v + pre;                 // global inclusive prefix
    lbase[tid] = inc - myc;
    gbs[tid] = myc ? atomicAdd(&cursor[tid], myc) : 0;
    int nvalid = tot;
    __syncthreads();
    #pragma unroll
    for (int i = 0; i < 8; ++i) {
        if (mask & (1u << i)) {
            int b = pk[i] >> 23;
            stage[lbase[b] + rk[i]] = pk[i];
        }
    }
    __syncthreads();
    for (int i = tid; i < nvalid; i += 512) {
        unsigned int v2 = stage[i];
        int b = v2 >> 23;
        binned[(size_t)b * BCAP + gbs[b] + (i - lbase[b])] = v2;   // regular: binB reuses
    }
}

// binB: one block per 128-node bucket. Single pass with rank recording.
__global__ __launch_bounds__(512)
void k_binB(const unsigned int* __restrict__ binned, const int* __restrict__ cursor,
            int* __restrict__ rowbeg, int* __restrict__ rowend, float* __restrict__ dinvg,
            unsigned short* __restrict__ csr, __half* __restrict__ hh, int N) {
    __shared__ int cnt[128];
    __shared__ int excls[128];
    __shared__ float dv[128];
    __shared__ int wsum2[2];
    int tid = threadIdx.x;
    int b = blockIdx.x;
    size_t ebase = (size_t)b * BCAP;
    int ne = cursor[b];
    if (tid < 128) cnt[tid] = 0;
    __syncthreads();
    unsigned int pk[16];
    int rk[16];
    #pragma unroll
    for (int ii = 0; ii < 16; ++ii) {
        int i = ii * 512 + tid;
        if (i < ne) {
            pk[ii] = binned[ebase + i];
            rk[ii] = atomicAdd(&cnt[(pk[ii] >> 16) & 127], 1);
        }
    }
    __syncthreads();
    int myc = 0, pcnt = 0;
    if (tid < 128) {
        myc = cnt[tid];
        pcnt = (myc + 1 + 7) & ~7;   // self + edges, padded to x8 (region layout)
    }
    int lid = tid & 63, wid2 = tid >> 6;
    int v = pcnt;
    if (tid < 128) {
        #pragma unroll
        for (int d = 1; d < 64; d <<= 1) {
            int u = __shfl_up(v, d, 64);
            if (lid >= d) v += u;
        }
        if (lid == 63) wsum2[wid2] = v;
    }
    __syncthreads();
    if (tid < 128 && wid2 == 1) v += wsum2[0];
    int cbase = b * CCAP;
    if (tid < 128) {
        int pexcl = v - pcnt;
        excls[tid] = pexcl;
        int node = (b << 7) + tid;
        int rb = cbase + pexcl;
        float di = rsqrtf((float)(myc + 1));
        dv[tid] = di;
        if (node < N) {
            rowbeg[node] = rb;
            rowend[node] = rb + 1 + myc;   // EXACT end (pads excluded)
            dinvg[node] = di;
            csr[rb] = (unsigned short)node;   // self entry first
        }
    }
    __syncthreads();
    #pragma unroll
    for (int ii = 0; ii < 16; ++ii) {
        int i = ii * 512 + tid;
        if (i < ne) {
            int nl = (pk[ii] >> 16) & 127;
            csr[cbase + excls[nl] + 1 + rk[ii]] = (unsigned short)(pk[ii] & 0xFFFFu);
        }
    }
    __syncthreads();
    if (tid < 128) {   // fill pad slots with dummy node N (zero row)
        int pexcl = excls[tid];
        for (int p = pexcl + 1 + myc; p < pexcl + pcnt; ++p)
            csr[cbase + p] = (unsigned short)N;
    }
    __syncthreads();
    // scale h rows of this bucket by dinv (fp16 in place): 128 rows x 4 uint4
    uint4* h4 = reinterpret_cast<uint4*>(hh);
    size_t hbase = (size_t)(b << 7) * 4;
    {
        int nl = tid >> 2;
        if (((b << 7) + nl) < N) {
            uint4 vv = h4[hbase + tid];
            float d = dv[nl];
            __half2* hv = reinterpret_cast<__half2*>(&vv);
            #pragma unroll
            for (int t = 0; t < 4; ++t) {
                float2 f = __half22float2(hv[t]);
                hv[t] = __floats2half2_rn(f.x * d, f.y * d);
            }
            h4[hbase + tid] = vv;
        }
    }
}

// fp16 -> fp32 accumulate in ONE instruction per feature: v_fma_mix_f32
#define MIXLO(ACC, U) asm("v_fma_mix_f32 %0, %1, 1.0, %0 op_sel:[0,0,0] op_sel_hi:[1,0,0]" : "+v"(ACC) : "v"(U))
#define MIXHI(ACC, U) asm("v_fma_mix_f32 %0, %1, 1.0, %0 op_sel:[1,0,0] op_sel_hi:[1,0,0]" : "+v"(ACC) : "v"(U))
#define ACC8M(A, V) do {            \
    MIXLO((A)[0], (V).x); MIXHI((A)[1], (V).x); \
    MIXLO((A)[2], (V).y); MIXHI((A)[3], (V).y); \
    MIXLO((A)[4], (V).z); MIXHI((A)[5], (V).z); \
    MIXLO((A)[6], (V).w); MIXHI((A)[7], (V).w); \
} while (0)

// Gather loop: 8 entries/iter; csr indices read NON-TEMPORALLY (single-touch,
// full-line 16B sequential stream) so the 3.2MB hp table keeps L2 residency.
#define AGG_GATHER_LOOP(beg_, endx_, h_)                                      \
    int t = (beg_) + 8 * (h_);                                                \
    if (t < (endx_)) {                                                        \
        u32x4 c4 = __builtin_nontemporal_load(                                \
            reinterpret_cast<const u32x4*>(csr + t));                         \
        while (t < (endx_)) {                                                 \
            int tn = t + 16;                                                  \
            int tc = (tn < (endx_)) ? tn : t;   /* clamp: stay in-bounds */   \
            u32x4 c4n = __builtin_nontemporal_load(                           \
                reinterpret_cast<const u32x4*>(csr + tc));                    \
            unsigned a0 = c4[0] & 0xFFFFu, a1 = c4[0] >> 16;                  \
            unsigned a2 = c4[1] & 0xFFFFu, a3 = c4[1] >> 16;                  \
            unsigned a4 = c4[2] & 0xFFFFu, a5 = c4[2] >> 16;                  \
            unsigned a6 = c4[3] & 0xFFFFu, a7 = c4[3] >> 16;                  \
            uint4 v0 = hp4[(size_t)a0 * 4 + q];                               \
            uint4 v1 = hp4[(size_t)a1 * 4 + q];                               \
            uint4 v2 = hp4[(size_t)a2 * 4 + q];                               \
            uint4 v3 = hp4[(size_t)a3 * 4 + q];                               \
            uint4 v4 = hp4[(size_t)a4 * 4 + q];                               \
            uint4 v5 = hp4[(size_t)a5 * 4 + q];                               \
            uint4 v6 = hp4[(size_t)a6 * 4 + q];                               \
            uint4 v7 = hp4[(size_t)a7 * 4 + q];                               \
            ACC8M(acc, v0); ACC8M(accB, v1); ACC8M(acc, v2); ACC8M(accB, v3); \
            ACC8M(acc, v4); ACC8M(accB, v5); ACC8M(acc, v6); ACC8M(accB, v7); \
            c4 = c4n;                                                         \
            t = tn;                                                           \
        }                                                                     \
    }

// Two-phase partial combine (h=0 writes, h=1 adds): no LDS atomics.
#define AGG_COMBINE()                                                         \
    if (h == 0) {                                                             \
        _Pragma("unroll")                                                     \
        for (int j2 = 0; j2 < 8; ++j2)                                        \
            aggT[q * 8 + j2][node_loc] = acc[j2] + accB[j2];                  \
    }                                                                         \
    __syncthreads();                                                          \
    if (h == 1) {                                                             \
        _Pragma("unroll")                                                     \
        for (int j2 = 0; j2 < 8; ++j2)                                        \
            aggT[q * 8 + j2][node_loc] += acc[j2] + accB[j2];                 \
    }                                                                         \
    __syncthreads();

// agg layer1 + bias + relu + gemm2 + dinv pre-scale.
__global__ __launch_bounds__(256)
void k_aggmm1(const __half* __restrict__ hp, const int* __restrict__ rowbeg,
              const int* __restrict__ rowend, const unsigned short* __restrict__ csr,
              const float* __restrict__ dinv, const float* __restrict__ b1,
              const float* __restrict__ W2, __half* __restrict__ hp2, int N) {
    __shared__ float aggT[32][33];    // [feature][node], pitch 33
    __shared__ float W2sh[32 * 32];   // 4 KB
    int tid = threadIdx.x;
    int lane = tid & 63;
    int w = tid >> 6;
    int g = lane >> 2, q = lane & 3;
    int h = w & 1;                    // row-split half (8-entry blocks interleaved)
    int node_loc = (w >> 1) * 16 + g; // 0..31
    int node = (int)blockIdx.x * 32 + node_loc;

    for (int i = tid; i < 256; i += 256)
        reinterpret_cast<float4*>(W2sh)[i] = reinterpret_cast<const float4*>(W2)[i];

    float acc[8], accB[8];
    #pragma unroll
    for (int t = 0; t < 8; ++t) { acc[t] = 0.f; accB[t] = 0.f; }
    int beg = 0, endx = 0;
    if (node < N) { beg = rowbeg[node]; endx = rowend[node]; }
    const uint4* hp4 = reinterpret_cast<const uint4*>(hp);
    AGG_GATHER_LOOP(beg, endx, h)
    AGG_COMBINE()

    // epilogue: 8 threads/node, 4 outcols each
    int nl2 = tid >> 3;               // 0..31
    int cgrp = tid & 7;               // cols cgrp*4..+3
    int onode = (int)blockIdx.x * 32 + nl2;
    float dd = (onode < N) ? dinv[onode] : 0.f;
    float o0 = 0.f, o1 = 0.f, o2 = 0.f, o3 = 0.f;
    #pragma unroll
    for (int k = 0; k < 32; ++k) {
        float yk = fmaxf(aggT[k][nl2] * dd + b1[k], 0.f);
        float4 wv = *reinterpret_cast<const float4*>(&W2sh[k * 32 + cgrp * 4]);
        o0 += yk * wv.x; o1 += yk * wv.y; o2 += yk * wv.z; o3 += yk * wv.w;
    }
    if (onode <= N) {   // node N: dd=0 -> stores zeros (pad row for layer-2 gathers)
        __half2 pa = __floats2half2_rn(o0 * dd, o1 * dd);
        __half2 pb = __floats2half2_rn(o2 * dd, o3 * dd);
        uint2 st;
        st.x = *reinterpret_cast<unsigned int*>(&pa);
        st.y = *reinterpret_cast<unsigned int*>(&pb);
        *reinterpret_cast<uint2*>(hp2 + (size_t)onode * 32 + cgrp * 4) = st;
    }
}

// agg layer2 + bias + relu + head (64 outcols). Same gather structure.
__global__ __launch_bounds__(256)
void k_aggout(const __half* __restrict__ hp, const int* __restrict__ rowbeg,
              const int* __restrict__ rowend, const unsigned short* __restrict__ csr,
              const float* __restrict__ dinv, const float* __restrict__ b2,
              const float* __restrict__ Wo, const float* __restrict__ bo,
              float* __restrict__ out, int N) {
    __shared__ float aggT[32][33];
    __shared__ float Wosh[32 * 64];   // 8 KB
    int tid = threadIdx.x;
    int lane = tid & 63;
    int w = tid >> 6;
    int g = lane >> 2, q = lane & 3;
    int h = w & 1;
    int node_loc = (w >> 1) * 16 + g;
    int node = (int)blockIdx.x * 32 + node_loc;

    for (int i = tid; i < 512; i += 256)
        reinterpret_cast<float4*>(Wosh)[i] = reinterpret_cast<const float4*>(Wo)[i];

    float acc[8], accB[8];
    #pragma unroll
    for (int t = 0; t < 8; ++t) { acc[t] = 0.f; accB[t] = 0.f; }
    int beg = 0, endx = 0;
    if (node < N) { beg = rowbeg[node]; endx = rowend[node]; }
    const uint4* hp4 = reinterpret_cast<const uint4*>(hp);
    AGG_GATHER_LOOP(beg, endx, h)
    AGG_COMBINE()

    // epilogue: 8 threads/node, 8 outcols each
    int nl2 = tid >> 3;
    int cgrp = tid & 7;               // cols cgrp*8..+7
    int onode = (int)blockIdx.x * 32 + nl2;
    float dd = (onode < N) ? dinv[onode] : 0.f;
    float o[8];
    #pragma unroll
    for (int i = 0; i < 8; ++i) o[i] = 0.f;
    #pragma unroll
    for (int k = 0; k < 32; ++k) {
        float yk = fmaxf(aggT[k][nl2] * dd + b2[k], 0.f);
        float4 wa = *reinterpret_cast<const float4*>(&Wosh[k * 64 + cgrp * 8]);
        float4 wb = *reinterpret_cast<const float4*>(&Wosh[k * 64 + cgrp * 8 + 4]);
        o[0] += yk * wa.x; o[1] += yk * wa.y; o[2] += yk * wa.z; o[3] += yk * wa.w;
        o[4] += yk * wb.x; o[5] += yk * wb.y; o[6] += yk * wb.z; o[7] += yk * wb.w;
    }
    if (onode < N) {
        float4 ba = *reinterpret_cast<const float4*>(bo + cgrp * 8);
        float4 bb = *reinterpret_cast<const float4*>(bo + cgrp * 8 + 4);
        float4 s0 = make_float4(o[0] + ba.x, o[1] + ba.y, o[2] + ba.z, o[3] + ba.w);
        float4 s1 = make_float4(o[4] + bb.x, o[5] + bb.y, o[6] + bb.z, o[7] + bb.w);
        float4* op = reinterpret_cast<float4*>(out + (size_t)onode * 64 + cgrp * 8);
        op[0] = s0;
        op[1] = s1;
    }
}

extern "C" void kernel_launch(void* const* d_in, const int* in_sizes, int n_in,
                              void* d_out, int out_size, void* d_ws, size_t ws_size,
                              hipStream_t stream) {
    const float* x  = (const float*)d_in[0];
    const int*   ei = (const int*)d_in[1];
    const float* W1 = (const float*)d_in[2];
    const float* b1 = (const float*)d_in[3];
    const float* W2 = (const float*)d_in[4];
    const float* b2 = (const float*)d_in[5];
    const float* Wo = (const float*)d_in[6];
    const float* bo = (const float*)d_in[7];
    float* out = (float*)d_out;

    const int N = in_sizes[0] / 128;   // 50000
    const int E = in_sizes[1] / 2;     // 1600000
    const int* src = ei;
    const int* dst = ei + E;

    char* ws = (char*)d_ws;
    size_t off = 0;
    auto alloc = [&](size_t bytes) {
        void* p = ws + off;
        off += (bytes + 255) & ~(size_t)255;
        return p;
    };
    int*            cursor = (int*)           alloc(512 * 4);
    unsigned int*   binned = (unsigned int*)  alloc((size_t)NBUCK * BCAP * 4);
    int*            rowbeg = (int*)           alloc((size_t)N * 4);
    int*            rowend = (int*)           alloc((size_t)N * 4);
    float*          dinv   = (float*)         alloc((size_t)N * 4);
    unsigned short* csr    = (unsigned short*)alloc((size_t)NBUCK * CCAP * 2);
    __half*         bufAh  = (__half*)        alloc((size_t)(N + 1) * 32 * 2);
    __half*         bufBh  = (__half*)        alloc((size_t)(N + 1) * 32 * 2);

    const int nbinA  = (E + CHUNK - 1) / CHUNK;      // 391
    const int nFront = NGEMM + nbinA;                // 587
    const int gAgg1  = (N + 1 + 31) / 32;            // covers pad node N
    const int gAgg2  = (N + 31) / 32;

    hipMemsetAsync(cursor, 0, 512 * 4, stream);
    k_front<<<nFront, 512, 0, stream>>>(x, W1, bufAh, N, src, dst, E,
                                        cursor, binned);
    k_binB<<<NBUCK, 512, 0, stream>>>(binned, cursor, rowbeg, rowend, dinv,
                                      csr, bufAh, N);
    k_aggmm1<<<gAgg1, 256, 0, stream>>>(bufAh, rowbeg, rowend, csr, dinv, b1,
                                        W2, bufBh, N);
    k_aggout<<<gAgg2, 256, 0, stream>>>(bufBh, rowbeg, rowend, csr, dinv, b2,
                                        Wo, bo, out, N);
}